// Round 1
// baseline (718.713 us; speedup 1.0000x reference)
//
#include <hip/hip_runtime.h>
#include <math.h>

#define F 128

// ---------------- spectral norm: one power iteration ----------------
// v = l2norm(W^T u); t = W v; sigma = ||t||^2 / (||t|| + 1e-12); out = 1/sigma
__global__ __launch_bounds__(128) void spectral_k(const float* __restrict__ W,
                                                  const float* __restrict__ u,
                                                  float* __restrict__ inv_sigma) {
    __shared__ float sv[F];
    __shared__ float red[F];
    __shared__ float snorm;
    int t = threadIdx.x;  // 128 threads
    // s = (W^T u)[t]
    float s = 0.f;
    for (int i = 0; i < F; ++i) s += W[i * F + t] * u[i];
    red[t] = s * s;
    __syncthreads();
    if (t == 0) {
        float a = 0.f;
        for (int i = 0; i < F; ++i) a += red[i];
        snorm = sqrtf(a);
    }
    __syncthreads();
    sv[t] = s / (snorm + 1e-12f);  // v
    __syncthreads();
    // t_i = (W v)[t]
    float s2 = 0.f;
    for (int j = 0; j < F; ++j) s2 += W[t * F + j] * sv[j];
    red[t] = s2 * s2;
    __syncthreads();
    if (t == 0) {
        float a = 0.f;
        for (int i = 0; i < F; ++i) a += red[i];
        float nt = sqrtf(a);
        float sigma = a / (nt + 1e-12f);  // u1 . (W v)
        inv_sigma[0] = 1.0f / sigma;
    }
}

// ---------------- degree ----------------
__global__ __launch_bounds__(256) void deg_init_k(float* __restrict__ deg, int n) {
    int i = blockIdx.x * 256 + threadIdx.x;
    if (i < n) deg[i] = 1.0f;  // self-loop weight
}

__global__ __launch_bounds__(256) void deg_edges_k(const int* __restrict__ col,
                                                   const float* __restrict__ wt,
                                                   float* __restrict__ deg, int e_cnt) {
    int e = blockIdx.x * 256 + threadIdx.x;
    if (e < e_cnt) {
        float w = 1.0f / (1.0f + expf(-wt[e]));  // sigmoid
        atomicAdd(deg + col[e], w);
    }
}

__global__ __launch_bounds__(256) void dinv_k(float* __restrict__ deg, int n) {
    int i = blockIdx.x * 256 + threadIdx.x;
    if (i < n) {
        float d = deg[i];
        deg[i] = (d > 0.f) ? (1.0f / sqrtf(d)) : 0.0f;
    }
}

// ---------------- self-loop init: agg = dinv^2 * x ----------------
__global__ __launch_bounds__(256) void agg_init_k(const float* __restrict__ x,
                                                  const float* __restrict__ dinv,
                                                  float* __restrict__ agg, int n) {
    int t = blockIdx.x * 256 + threadIdx.x;  // over n*32 float4 chunks
    if (t < n * 32) {
        int node = t >> 5;
        int q = (t & 31) * 4;
        float dv = dinv[node];
        float s = dv * dv;
        float4 xv = *(const float4*)(x + node * F + q);
        float4 o = make_float4(s * xv.x, s * xv.y, s * xv.z, s * xv.w);
        *(float4*)(agg + node * F + q) = o;
    }
}

// ---------------- edge scatter: agg[col] += norm_e * x[row] ----------------
// one wave (64 lanes) per edge; float2 per lane covers 128 floats
__global__ __launch_bounds__(256) void scatter_k(const int* __restrict__ row,
                                                 const int* __restrict__ col,
                                                 const float* __restrict__ wt,
                                                 const float* __restrict__ dinv,
                                                 const float* __restrict__ x,
                                                 float* __restrict__ agg, int e_cnt) {
    int e = blockIdx.x * 4 + (threadIdx.x >> 6);
    if (e >= e_cnt) return;
    int lane = threadIdx.x & 63;
    int r = row[e];
    int c = col[e];
    float w = 1.0f / (1.0f + expf(-wt[e]));
    float nv = dinv[r] * w * dinv[c];
    float2 xv = *(const float2*)(x + r * F + lane * 2);
    atomicAdd(agg + c * F + lane * 2, nv * xv.x);
    atomicAdd(agg + c * F + lane * 2 + 1, nv * xv.y);
}

// ---------------- in-place GEMM: io = io @ (W * inv_sigma) + bias ----------------
// block = 256 threads handles BM=64 rows; stages its rows into LDS (transposed)
// then overwrites them. W staged in BK=32 k-chunks. 48KB LDS -> 3 blocks/CU.
#define BM 64
#define BK 32
__global__ __launch_bounds__(256) void gemm_inplace_k(float* __restrict__ io,
                                                      const float* __restrict__ W,
                                                      const float* __restrict__ invs,
                                                      const float* __restrict__ bias,
                                                      int nrows) {
    __shared__ float xs[F * BM];    // [k][row] 32KB
    __shared__ float wsh[BK * F];   // [k][col] 16KB
    int tid = threadIdx.x;
    int rowBase = blockIdx.x * BM;
    float is = invs[0];

    // stage x rows (transposed into LDS)
    for (int i = tid; i < BM * 32; i += 256) {
        int r = i >> 5;
        int k4 = (i & 31) * 4;
        int gr = rowBase + r;
        float4 xv = make_float4(0.f, 0.f, 0.f, 0.f);
        if (gr < nrows) xv = *(const float4*)(io + gr * F + k4);
        xs[(k4 + 0) * BM + r] = xv.x;
        xs[(k4 + 1) * BM + r] = xv.y;
        xs[(k4 + 2) * BM + r] = xv.z;
        xs[(k4 + 3) * BM + r] = xv.w;
    }

    int tx = tid & 15, ty = tid >> 4;
    int r0 = tx * 4, c0 = ty * 8;
    float acc[4][8] = {};

    for (int kc = 0; kc < F; kc += BK) {
        __syncthreads();  // iter0: xs staged; later: wsh consumers done
        for (int i = tid; i < BK * 32; i += 256) {
            int kk = i >> 5;
            int j4 = (i & 31) * 4;
            float4 wv = *(const float4*)(W + (kc + kk) * F + j4);
            wv.x *= is; wv.y *= is; wv.z *= is; wv.w *= is;
            *(float4*)(wsh + kk * F + j4) = wv;
        }
        __syncthreads();
#pragma unroll
        for (int k = 0; k < BK; ++k) {
            float4 xv = *(float4*)(xs + (kc + k) * BM + r0);
            float4 wa = *(float4*)(wsh + k * F + c0);
            float4 wb = *(float4*)(wsh + k * F + c0 + 4);
            float xr[4] = {xv.x, xv.y, xv.z, xv.w};
            float wc[8] = {wa.x, wa.y, wa.z, wa.w, wb.x, wb.y, wb.z, wb.w};
#pragma unroll
            for (int rr = 0; rr < 4; ++rr)
#pragma unroll
                for (int cc = 0; cc < 8; ++cc)
                    acc[rr][cc] = fmaf(xr[rr], wc[cc], acc[rr][cc]);
        }
    }

    float4 bv0 = *(const float4*)(bias + c0);
    float4 bv1 = *(const float4*)(bias + c0 + 4);
#pragma unroll
    for (int rr = 0; rr < 4; ++rr) {
        int gr = rowBase + r0 + rr;
        if (gr < nrows) {
            float4 o0 = make_float4(acc[rr][0] + bv0.x, acc[rr][1] + bv0.y,
                                    acc[rr][2] + bv0.z, acc[rr][3] + bv0.w);
            float4 o1 = make_float4(acc[rr][4] + bv1.x, acc[rr][5] + bv1.y,
                                    acc[rr][6] + bv1.z, acc[rr][7] + bv1.w);
            *(float4*)(io + gr * F + c0) = o0;
            *(float4*)(io + gr * F + c0 + 4) = o1;
        }
    }
}

extern "C" void kernel_launch(void* const* d_in, const int* in_sizes, int n_in,
                              void* d_out, int out_size, void* d_ws, size_t ws_size,
                              hipStream_t stream) {
    const float* x    = (const float*)d_in[0];
    const int*   ei   = (const int*)d_in[1];
    const float* ewt  = (const float*)d_in[2];
    const float* W    = (const float*)d_in[3];
    const float* bias = (const float*)d_in[4];
    const float* u    = (const float*)d_in[5];
    float* out = (float*)d_out;

    int n_nodes = in_sizes[0] / F;
    int e_cnt   = in_sizes[2];
    const int* row = ei;
    const int* col = ei + e_cnt;

    float* wsf  = (float*)d_ws;
    float* invs = wsf;        // 1 float (padded to 64)
    float* deg  = wsf + 64;   // n_nodes floats; becomes dinv in place

    spectral_k<<<1, 128, 0, stream>>>(W, u, invs);
    deg_init_k<<<(n_nodes + 255) / 256, 256, 0, stream>>>(deg, n_nodes);
    deg_edges_k<<<(e_cnt + 255) / 256, 256, 0, stream>>>(col, ewt, deg, e_cnt);
    dinv_k<<<(n_nodes + 255) / 256, 256, 0, stream>>>(deg, n_nodes);
    agg_init_k<<<(n_nodes * 32 + 255) / 256, 256, 0, stream>>>(x, deg, out, n_nodes);
    scatter_k<<<(e_cnt + 3) / 4, 256, 0, stream>>>(row, col, ewt, deg, x, out, e_cnt);
    gemm_inplace_k<<<(n_nodes + BM - 1) / BM, 256, 0, stream>>>(out, W, invs, bias, n_nodes);
}

// Round 2
// 348.760 us; speedup vs baseline: 2.0608x; 2.0608x over previous
//
#include <hip/hip_runtime.h>
#include <math.h>

#define F 128

// ---------------- spectral norm: one power iteration ----------------
__global__ __launch_bounds__(128) void spectral_k(const float* __restrict__ W,
                                                  const float* __restrict__ u,
                                                  float* __restrict__ inv_sigma) {
    __shared__ float sv[F];
    __shared__ float red[F];
    __shared__ float snorm;
    int t = threadIdx.x;  // 128 threads
    float s = 0.f;
    for (int i = 0; i < F; ++i) s += W[i * F + t] * u[i];
    red[t] = s * s;
    __syncthreads();
    if (t == 0) {
        float a = 0.f;
        for (int i = 0; i < F; ++i) a += red[i];
        snorm = sqrtf(a);
    }
    __syncthreads();
    sv[t] = s / (snorm + 1e-12f);  // v
    __syncthreads();
    float s2 = 0.f;
    for (int j = 0; j < F; ++j) s2 += W[t * F + j] * sv[j];
    red[t] = s2 * s2;
    __syncthreads();
    if (t == 0) {
        float a = 0.f;
        for (int i = 0; i < F; ++i) a += red[i];
        float nt = sqrtf(a);
        float sigma = a / (nt + 1e-12f);
        inv_sigma[0] = 1.0f / sigma;
    }
}

// ---------------- init: deg=1 (self loop), cnt=0 ----------------
__global__ __launch_bounds__(256) void init_k(float* __restrict__ deg, int* __restrict__ cnt, int n) {
    int i = blockIdx.x * 256 + threadIdx.x;
    if (i < n) { deg[i] = 1.0f; cnt[i] = 0; }
}

// ---------------- per-edge: weighted degree + in-degree count ----------------
__global__ __launch_bounds__(256) void count_k(const int* __restrict__ col,
                                               const float* __restrict__ wt,
                                               float* __restrict__ deg,
                                               int* __restrict__ cnt, int e_cnt) {
    int e = blockIdx.x * 256 + threadIdx.x;
    if (e < e_cnt) {
        int c = col[e];
        float w = 1.0f / (1.0f + expf(-wt[e]));  // sigmoid
        atomicAdd(deg + c, w);
        atomicAdd(cnt + c, 1);
    }
}

__global__ __launch_bounds__(256) void dinv_k(float* __restrict__ deg, int n) {
    int i = blockIdx.x * 256 + threadIdx.x;
    if (i < n) {
        float d = deg[i];
        deg[i] = (d > 0.f) ? (1.0f / sqrtf(d)) : 0.0f;
    }
}

// ---------------- exclusive scan of cnt -> offsets (3 passes, tile=1024) ----------------
#define STILE 1024
__global__ __launch_bounds__(256) void scan1_k(const int* __restrict__ cnt,
                                               int* __restrict__ bsum, int n) {
    __shared__ int red[256];
    int t = threadIdx.x;
    int base = blockIdx.x * STILE + t * 4;
    int s = 0;
    if (base + 3 < n) { int4 v = *(const int4*)(cnt + base); s = v.x + v.y + v.z + v.w; }
    else { for (int i = 0; i < 4; ++i) if (base + i < n) s += cnt[base + i]; }
    red[t] = s;
    __syncthreads();
    for (int o = 128; o > 0; o >>= 1) { if (t < o) red[t] += red[t + o]; __syncthreads(); }
    if (t == 0) bsum[blockIdx.x] = red[0];
}

__global__ void scan2_k(int* __restrict__ bsum, int g, int* __restrict__ offsets, int n) {
    if (threadIdx.x == 0 && blockIdx.x == 0) {
        int acc = 0;
        for (int i = 0; i < g; ++i) { int v = bsum[i]; bsum[i] = acc; acc += v; }
        offsets[n] = acc;  // == E
    }
}

__global__ __launch_bounds__(256) void scan3_k(const int* __restrict__ cnt,
                                               const int* __restrict__ bsum,
                                               int* __restrict__ offsets,
                                               int* __restrict__ cursor, int n) {
    __shared__ int sc[256];
    int t = threadIdx.x;
    int base = blockIdx.x * STILE + t * 4;
    int v[4] = {0, 0, 0, 0};
    if (base + 3 < n) { int4 q = *(const int4*)(cnt + base); v[0] = q.x; v[1] = q.y; v[2] = q.z; v[3] = q.w; }
    else { for (int i = 0; i < 4; ++i) if (base + i < n) v[i] = cnt[base + i]; }
    int ts = v[0] + v[1] + v[2] + v[3];
    sc[t] = ts;
    __syncthreads();
    // inclusive Hillis-Steele over 256 thread sums
    for (int o = 1; o < 256; o <<= 1) {
        int val = sc[t];
        int add = (t >= o) ? sc[t - o] : 0;
        __syncthreads();
        sc[t] = val + add;
        __syncthreads();
    }
    int run = bsum[blockIdx.x] + sc[t] - ts;  // exclusive base for this thread
    for (int i = 0; i < 4; ++i) {
        if (base + i < n) { offsets[base + i] = run; cursor[base + i] = run; }
        run += v[i];
    }
}

// ---------------- counting-sort fill: (src, norm) per destination bucket ----------------
__global__ __launch_bounds__(256) void fill_k(const int* __restrict__ row,
                                              const int* __restrict__ col,
                                              const float* __restrict__ wt,
                                              const float* __restrict__ dinv,
                                              int* __restrict__ cursor,
                                              int* __restrict__ srcs,
                                              float* __restrict__ nrms, int e_cnt) {
    int e = blockIdx.x * 256 + threadIdx.x;
    if (e < e_cnt) {
        int r = row[e], c = col[e];
        float w = 1.0f / (1.0f + expf(-wt[e]));
        float nv = dinv[r] * w * dinv[c];
        int p = atomicAdd(cursor + c, 1);
        srcs[p] = r;
        nrms[p] = nv;
    }
}

// ---------------- gather: one wave per destination node, no atomics ----------------
__global__ __launch_bounds__(256) void gather_k(const int* __restrict__ offsets,
                                                const int* __restrict__ srcs,
                                                const float* __restrict__ nrms,
                                                const float* __restrict__ dinv,
                                                const float* __restrict__ x,
                                                float* __restrict__ out, int n) {
    int node = blockIdx.x * 4 + (threadIdx.x >> 6);
    if (node >= n) return;
    int lane = threadIdx.x & 63;
    const float2* x2 = (const float2*)x;
    float dv = dinv[node];
    float2 xv = x2[node * 64 + lane];
    float2 acc;
    acc.x = dv * dv * xv.x;  // self loop: norm = dinv*1*dinv
    acc.y = dv * dv * xv.y;
    int s = offsets[node], e = offsets[node + 1];
    for (int b = s; b < e; b += 64) {
        int cnt = min(64, e - b);
        int r_l = 0; float nv_l = 0.f;
        if (lane < cnt) { r_l = srcs[b + lane]; nv_l = nrms[b + lane]; }
        for (int j = 0; j < cnt; ++j) {
            int r = __shfl(r_l, j);
            float nv = __shfl(nv_l, j);
            float2 xr = x2[r * 64 + lane];
            acc.x = fmaf(nv, xr.x, acc.x);
            acc.y = fmaf(nv, xr.y, acc.y);
        }
    }
    ((float2*)out)[node * 64 + lane] = acc;
}

// ---------------- in-place GEMM: io = io @ (W * inv_sigma) + bias ----------------
#define BM 64
#define BK 32
__global__ __launch_bounds__(256) void gemm_inplace_k(float* __restrict__ io,
                                                      const float* __restrict__ W,
                                                      const float* __restrict__ invs,
                                                      const float* __restrict__ bias,
                                                      int nrows) {
    __shared__ float xs[F * BM];    // [k][row] 32KB
    __shared__ float wsh[BK * F];   // [k][col] 16KB
    int tid = threadIdx.x;
    int rowBase = blockIdx.x * BM;
    float is = invs[0];

    for (int i = tid; i < BM * 32; i += 256) {
        int r = i >> 5;
        int k4 = (i & 31) * 4;
        int gr = rowBase + r;
        float4 xv = make_float4(0.f, 0.f, 0.f, 0.f);
        if (gr < nrows) xv = *(const float4*)(io + gr * F + k4);
        xs[(k4 + 0) * BM + r] = xv.x;
        xs[(k4 + 1) * BM + r] = xv.y;
        xs[(k4 + 2) * BM + r] = xv.z;
        xs[(k4 + 3) * BM + r] = xv.w;
    }

    int tx = tid & 15, ty = tid >> 4;
    int r0 = tx * 4, c0 = ty * 8;
    float acc[4][8] = {};

    for (int kc = 0; kc < F; kc += BK) {
        __syncthreads();
        for (int i = tid; i < BK * 32; i += 256) {
            int kk = i >> 5;
            int j4 = (i & 31) * 4;
            float4 wv = *(const float4*)(W + (kc + kk) * F + j4);
            wv.x *= is; wv.y *= is; wv.z *= is; wv.w *= is;
            *(float4*)(wsh + kk * F + j4) = wv;
        }
        __syncthreads();
#pragma unroll
        for (int k = 0; k < BK; ++k) {
            float4 xv = *(float4*)(xs + (kc + k) * BM + r0);
            float4 wa = *(float4*)(wsh + k * F + c0);
            float4 wb = *(float4*)(wsh + k * F + c0 + 4);
            float xr[4] = {xv.x, xv.y, xv.z, xv.w};
            float wc[8] = {wa.x, wa.y, wa.z, wa.w, wb.x, wb.y, wb.z, wb.w};
#pragma unroll
            for (int rr = 0; rr < 4; ++rr)
#pragma unroll
                for (int cc = 0; cc < 8; ++cc)
                    acc[rr][cc] = fmaf(xr[rr], wc[cc], acc[rr][cc]);
        }
    }

    float4 bv0 = *(const float4*)(bias + c0);
    float4 bv1 = *(const float4*)(bias + c0 + 4);
#pragma unroll
    for (int rr = 0; rr < 4; ++rr) {
        int gr = rowBase + r0 + rr;
        if (gr < nrows) {
            float4 o0 = make_float4(acc[rr][0] + bv0.x, acc[rr][1] + bv0.y,
                                    acc[rr][2] + bv0.z, acc[rr][3] + bv0.w);
            float4 o1 = make_float4(acc[rr][4] + bv1.x, acc[rr][5] + bv1.y,
                                    acc[rr][6] + bv1.z, acc[rr][7] + bv1.w);
            *(float4*)(io + gr * F + c0) = o0;
            *(float4*)(io + gr * F + c0 + 4) = o1;
        }
    }
}

extern "C" void kernel_launch(void* const* d_in, const int* in_sizes, int n_in,
                              void* d_out, int out_size, void* d_ws, size_t ws_size,
                              hipStream_t stream) {
    const float* x    = (const float*)d_in[0];
    const int*   ei   = (const int*)d_in[1];
    const float* ewt  = (const float*)d_in[2];
    const float* W    = (const float*)d_in[3];
    const float* bias = (const float*)d_in[4];
    const float* u    = (const float*)d_in[5];
    float* out = (float*)d_out;

    int n_nodes = in_sizes[0] / F;
    int e_cnt   = in_sizes[2];
    const int* row = ei;
    const int* col = ei + e_cnt;

    // workspace layout (4B elements)
    float* wsf = (float*)d_ws;
    int*   wsi = (int*)d_ws;
    float* invs    = wsf;                          // 64
    float* dinv    = wsf + 64;                     // N  (deg -> dinv in place)
    int*   cnt     = wsi + 64 + n_nodes;           // N
    int*   offsets = cnt + n_nodes;                // N+1
    int*   cursor  = offsets + n_nodes + 1;        // N
    int*   bsum    = cursor + n_nodes;             // 128
    int*   srcs    = bsum + 128;                   // E
    float* nrms    = (float*)(srcs + e_cnt);       // E

    int g_scan = (n_nodes + STILE - 1) / STILE;

    spectral_k<<<1, 128, 0, stream>>>(W, u, invs);
    init_k<<<(n_nodes + 255) / 256, 256, 0, stream>>>(dinv, cnt, n_nodes);
    count_k<<<(e_cnt + 255) / 256, 256, 0, stream>>>(col, ewt, dinv, cnt, e_cnt);
    dinv_k<<<(n_nodes + 255) / 256, 256, 0, stream>>>(dinv, n_nodes);
    scan1_k<<<g_scan, 256, 0, stream>>>(cnt, bsum, n_nodes);
    scan2_k<<<1, 64, 0, stream>>>(bsum, g_scan, offsets, n_nodes);
    scan3_k<<<g_scan, 256, 0, stream>>>(cnt, bsum, offsets, cursor, n_nodes);
    fill_k<<<(e_cnt + 255) / 256, 256, 0, stream>>>(row, col, ewt, dinv, cursor, srcs, nrms, e_cnt);
    gather_k<<<(n_nodes + 3) / 4, 256, 0, stream>>>(offsets, srcs, nrms, dinv, x, out, n_nodes);
    gemm_inplace_k<<<(n_nodes + BM - 1) / BM, 256, 0, stream>>>(out, W, invs, bias, n_nodes);
}

// Round 3
// 314.663 us; speedup vs baseline: 2.2841x; 1.1084x over previous
//
#include <hip/hip_runtime.h>
#include <math.h>

#define F 128

typedef __bf16 bf16_t;
typedef __attribute__((ext_vector_type(8))) bf16_t bf16x8;
typedef __attribute__((ext_vector_type(4))) bf16_t bf16x4;
typedef __attribute__((ext_vector_type(4))) float floatx4;

// ---------------- spectral norm: one power iteration ----------------
__global__ __launch_bounds__(128) void spectral_k(const float* __restrict__ W,
                                                  const float* __restrict__ u,
                                                  float* __restrict__ inv_sigma) {
    __shared__ float sv[F];
    __shared__ float red[F];
    __shared__ float snorm;
    int t = threadIdx.x;  // 128 threads
    float s = 0.f;
    for (int i = 0; i < F; ++i) s += W[i * F + t] * u[i];
    red[t] = s * s;
    __syncthreads();
    if (t == 0) {
        float a = 0.f;
        for (int i = 0; i < F; ++i) a += red[i];
        snorm = sqrtf(a);
    }
    __syncthreads();
    sv[t] = s / (snorm + 1e-12f);  // v
    __syncthreads();
    float s2 = 0.f;
    for (int j = 0; j < F; ++j) s2 += W[t * F + j] * sv[j];
    red[t] = s2 * s2;
    __syncthreads();
    if (t == 0) {
        float a = 0.f;
        for (int i = 0; i < F; ++i) a += red[i];
        float nt = sqrtf(a);
        float sigma = a / (nt + 1e-12f);
        inv_sigma[0] = 1.0f / sigma;
    }
}

// ---------------- init: deg=1 (self loop), cnt=0 ----------------
__global__ __launch_bounds__(256) void init_k(float* __restrict__ deg, int* __restrict__ cnt, int n) {
    int i = blockIdx.x * 256 + threadIdx.x;
    if (i < n) { deg[i] = 1.0f; cnt[i] = 0; }
}

// ---------------- per-edge: weighted degree + in-degree count ----------------
__global__ __launch_bounds__(256) void count_k(const int* __restrict__ col,
                                               const float* __restrict__ wt,
                                               float* __restrict__ deg,
                                               int* __restrict__ cnt, int e_cnt) {
    int e = blockIdx.x * 256 + threadIdx.x;
    if (e < e_cnt) {
        int c = col[e];
        float w = 1.0f / (1.0f + expf(-wt[e]));  // sigmoid
        atomicAdd(deg + c, w);
        atomicAdd(cnt + c, 1);
    }
}

__global__ __launch_bounds__(256) void dinv_k(float* __restrict__ deg, int n) {
    int i = blockIdx.x * 256 + threadIdx.x;
    if (i < n) {
        float d = deg[i];
        deg[i] = (d > 0.f) ? (1.0f / sqrtf(d)) : 0.0f;
    }
}

// ---------------- exclusive scan of cnt -> offsets (3 passes, tile=1024) ----------------
#define STILE 1024
__global__ __launch_bounds__(256) void scan1_k(const int* __restrict__ cnt,
                                               int* __restrict__ bsum, int n) {
    __shared__ int red[256];
    int t = threadIdx.x;
    int base = blockIdx.x * STILE + t * 4;
    int s = 0;
    if (base + 3 < n) { int4 v = *(const int4*)(cnt + base); s = v.x + v.y + v.z + v.w; }
    else { for (int i = 0; i < 4; ++i) if (base + i < n) s += cnt[base + i]; }
    red[t] = s;
    __syncthreads();
    for (int o = 128; o > 0; o >>= 1) { if (t < o) red[t] += red[t + o]; __syncthreads(); }
    if (t == 0) bsum[blockIdx.x] = red[0];
}

__global__ void scan2_k(int* __restrict__ bsum, int g, int* __restrict__ offsets, int n) {
    if (threadIdx.x == 0 && blockIdx.x == 0) {
        int acc = 0;
        for (int i = 0; i < g; ++i) { int v = bsum[i]; bsum[i] = acc; acc += v; }
        offsets[n] = acc;  // == E
    }
}

__global__ __launch_bounds__(256) void scan3_k(const int* __restrict__ cnt,
                                               const int* __restrict__ bsum,
                                               int* __restrict__ offsets,
                                               int* __restrict__ cursor, int n) {
    __shared__ int sc[256];
    int t = threadIdx.x;
    int base = blockIdx.x * STILE + t * 4;
    int v[4] = {0, 0, 0, 0};
    if (base + 3 < n) { int4 q = *(const int4*)(cnt + base); v[0] = q.x; v[1] = q.y; v[2] = q.z; v[3] = q.w; }
    else { for (int i = 0; i < 4; ++i) if (base + i < n) v[i] = cnt[base + i]; }
    int ts = v[0] + v[1] + v[2] + v[3];
    sc[t] = ts;
    __syncthreads();
    for (int o = 1; o < 256; o <<= 1) {
        int val = sc[t];
        int add = (t >= o) ? sc[t - o] : 0;
        __syncthreads();
        sc[t] = val + add;
        __syncthreads();
    }
    int run = bsum[blockIdx.x] + sc[t] - ts;  // exclusive base for this thread
    for (int i = 0; i < 4; ++i) {
        if (base + i < n) { offsets[base + i] = run; cursor[base + i] = run; }
        run += v[i];
    }
}

// ---------------- counting-sort fill: (src, norm) per destination bucket ----------------
__global__ __launch_bounds__(256) void fill_k(const int* __restrict__ row,
                                              const int* __restrict__ col,
                                              const float* __restrict__ wt,
                                              const float* __restrict__ dinv,
                                              int* __restrict__ cursor,
                                              int* __restrict__ srcs,
                                              float* __restrict__ nrms, int e_cnt) {
    int e = blockIdx.x * 256 + threadIdx.x;
    if (e < e_cnt) {
        int r = row[e], c = col[e];
        float w = 1.0f / (1.0f + expf(-wt[e]));
        float nv = dinv[r] * w * dinv[c];
        int p = atomicAdd(cursor + c, 1);
        srcs[p] = r;
        nrms[p] = nv;
    }
}

// ---------------- gather: one wave per destination node, no atomics ----------------
__global__ __launch_bounds__(256) void gather_k(const int* __restrict__ offsets,
                                                const int* __restrict__ srcs,
                                                const float* __restrict__ nrms,
                                                const float* __restrict__ dinv,
                                                const float* __restrict__ x,
                                                float* __restrict__ out, int n) {
    int node = blockIdx.x * 4 + (threadIdx.x >> 6);
    if (node >= n) return;
    int lane = threadIdx.x & 63;
    const float2* x2 = (const float2*)x;
    float dv = dinv[node];
    float2 xv = x2[node * 64 + lane];
    float2 acc;
    acc.x = dv * dv * xv.x;  // self loop: norm = dinv*1*dinv
    acc.y = dv * dv * xv.y;
    int s = offsets[node], e = offsets[node + 1];
    for (int b = s; b < e; b += 64) {
        int cnt = min(64, e - b);
        int r_l = 0; float nv_l = 0.f;
        if (lane < cnt) { r_l = srcs[b + lane]; nv_l = nrms[b + lane]; }
        for (int j = 0; j < cnt; ++j) {
            int r = __shfl(r_l, j);
            float nv = __shfl(nv_l, j);
            float2 xr = x2[r * 64 + lane];
            acc.x = fmaf(nv, xr.x, acc.x);
            acc.y = fmaf(nv, xr.y, acc.y);
        }
    }
    ((float2*)out)[node * 64 + lane] = acc;
}

// ---------------- Wt[n][k] = bf16(W[k][n] * inv_sigma) ----------------
__global__ __launch_bounds__(256) void wt_k(const float* __restrict__ W,
                                            const float* __restrict__ invs,
                                            bf16_t* __restrict__ Wt) {
    float is = invs[0];
    int t = blockIdx.x * 256 + threadIdx.x;  // 16384 total
    int k = t >> 7, n = t & 127;
    Wt[n * F + k] = (bf16_t)(W[k * F + n] * is);
}

// ---------------- MFMA GEMM (in place): io = bf16(io) @ Wn + bias ----------------
// 64 rows/block, 4 waves x 16 rows; mfma_f32_16x16x32_bf16.
// LDS: As 64x136 bf16 (17KB) + Ws 128x136 bf16 (35KB) = 52KB -> 3 blocks/CU.
#define GBM 64
#define LDK 136  // 128 + 8 pad: frag reads land 2-way (free) on banks
__global__ __launch_bounds__(256) void gemm_mfma_k(float* __restrict__ io,
                                                   const bf16_t* __restrict__ Wt,
                                                   const float* __restrict__ bias,
                                                   int nrows) {
    __shared__ bf16_t As[GBM * LDK];
    __shared__ bf16_t Ws[F * LDK];
    int tid = threadIdx.x;
    int rowBase = blockIdx.x * GBM;

    // stage A rows: fp32 -> bf16 (RNE)
    for (int i = tid; i < GBM * 32; i += 256) {  // float4 chunks
        int r = i >> 5, c4 = (i & 31) * 4;
        float4 xv = make_float4(0.f, 0.f, 0.f, 0.f);
        if (rowBase + r < nrows) xv = *(const float4*)(io + (rowBase + r) * F + c4);
        bf16x4 v;
        v.x = (bf16_t)xv.x; v.y = (bf16_t)xv.y; v.z = (bf16_t)xv.z; v.w = (bf16_t)xv.w;
        *(bf16x4*)(As + r * LDK + c4) = v;
    }
    // stage Wt (already bf16, [n][k]) with pad
    for (int i = tid; i < 2048; i += 256) {  // 16B chunks: 128 rows x 16
        int nrow = i >> 4;
        int c = (i & 15) * 8;
        *(bf16x8*)(Ws + nrow * LDK + c) = *(const bf16x8*)(Wt + nrow * F + c);
    }
    __syncthreads();

    int wave = tid >> 6, lane = tid & 63;
    int l16 = lane & 15, q = lane >> 4;
    int mrow = wave * 16;

    floatx4 acc[8];
#pragma unroll
    for (int nt = 0; nt < 8; ++nt) acc[nt] = (floatx4){0.f, 0.f, 0.f, 0.f};

#pragma unroll
    for (int kt = 0; kt < 4; ++kt) {
        bf16x8 a = *(bf16x8*)(As + (mrow + l16) * LDK + kt * 32 + q * 8);
#pragma unroll
        for (int nt = 0; nt < 8; ++nt) {
            bf16x8 b = *(bf16x8*)(Ws + (nt * 16 + l16) * LDK + kt * 32 + q * 8);
            acc[nt] = __builtin_amdgcn_mfma_f32_16x16x32_bf16(a, b, acc[nt], 0, 0, 0);
        }
    }

    // epilogue: C/D layout col = lane&15, row = q*4 + reg
#pragma unroll
    for (int nt = 0; nt < 8; ++nt) {
        int col = nt * 16 + l16;
        float bv = bias[col];
#pragma unroll
        for (int r = 0; r < 4; ++r) {
            int grow = rowBase + mrow + q * 4 + r;
            if (grow < nrows) io[grow * F + col] = acc[nt][r] + bv;
        }
    }
}

extern "C" void kernel_launch(void* const* d_in, const int* in_sizes, int n_in,
                              void* d_out, int out_size, void* d_ws, size_t ws_size,
                              hipStream_t stream) {
    const float* x    = (const float*)d_in[0];
    const int*   ei   = (const int*)d_in[1];
    const float* ewt  = (const float*)d_in[2];
    const float* W    = (const float*)d_in[3];
    const float* bias = (const float*)d_in[4];
    const float* u    = (const float*)d_in[5];
    float* out = (float*)d_out;

    int n_nodes = in_sizes[0] / F;
    int e_cnt   = in_sizes[2];
    const int* row = ei;
    const int* col = ei + e_cnt;

    // workspace layout (4B elements)
    float* wsf = (float*)d_ws;
    int*   wsi = (int*)d_ws;
    float* invs    = wsf;                          // 64
    float* dinv    = wsf + 64;                     // N  (deg -> dinv in place)
    int*   cnt     = wsi + 64 + n_nodes;           // N
    int*   offsets = cnt + n_nodes;                // N+1
    int*   cursor  = offsets + n_nodes + 1;        // N
    int*   bsum    = cursor + n_nodes;             // 128
    int*   srcs    = bsum + 128;                   // E
    float* nrms    = (float*)(srcs + e_cnt);       // E
    bf16_t* Wt     = (bf16_t*)(((size_t)(nrms + e_cnt) + 15) & ~(size_t)15);  // 128x128 bf16

    int g_scan = (n_nodes + STILE - 1) / STILE;

    spectral_k<<<1, 128, 0, stream>>>(W, u, invs);
    init_k<<<(n_nodes + 255) / 256, 256, 0, stream>>>(dinv, cnt, n_nodes);
    count_k<<<(e_cnt + 255) / 256, 256, 0, stream>>>(col, ewt, dinv, cnt, e_cnt);
    dinv_k<<<(n_nodes + 255) / 256, 256, 0, stream>>>(dinv, n_nodes);
    scan1_k<<<g_scan, 256, 0, stream>>>(cnt, bsum, n_nodes);
    scan2_k<<<1, 64, 0, stream>>>(bsum, g_scan, offsets, n_nodes);
    scan3_k<<<g_scan, 256, 0, stream>>>(cnt, bsum, offsets, cursor, n_nodes);
    fill_k<<<(e_cnt + 255) / 256, 256, 0, stream>>>(row, col, ewt, dinv, cursor, srcs, nrms, e_cnt);
    gather_k<<<(n_nodes + 3) / 4, 256, 0, stream>>>(offsets, srcs, nrms, dinv, x, out, n_nodes);
    wt_k<<<64, 256, 0, stream>>>(W, invs, Wt);
    gemm_mfma_k<<<(n_nodes + GBM - 1) / GBM, 256, 0, stream>>>(out, Wt, bias, n_nodes);
}

// Round 4
// 298.675 us; speedup vs baseline: 2.4063x; 1.0535x over previous
//
#include <hip/hip_runtime.h>
#include <math.h>

#define F 128

typedef __bf16 bf16_t;
typedef __attribute__((ext_vector_type(8))) bf16_t bf16x8;
typedef __attribute__((ext_vector_type(4))) bf16_t bf16x4;
typedef __attribute__((ext_vector_type(4))) float floatx4;

// ---------------- spectral norm: one power iteration ----------------
__global__ __launch_bounds__(128) void spectral_k(const float* __restrict__ W,
                                                  const float* __restrict__ u,
                                                  float* __restrict__ inv_sigma) {
    __shared__ float sv[F];
    __shared__ float red[F];
    __shared__ float snorm;
    int t = threadIdx.x;  // 128 threads
    float s = 0.f;
    for (int i = 0; i < F; ++i) s += W[i * F + t] * u[i];
    red[t] = s * s;
    __syncthreads();
    if (t == 0) {
        float a = 0.f;
        for (int i = 0; i < F; ++i) a += red[i];
        snorm = sqrtf(a);
    }
    __syncthreads();
    sv[t] = s / (snorm + 1e-12f);  // v
    __syncthreads();
    float s2 = 0.f;
    for (int j = 0; j < F; ++j) s2 += W[t * F + j] * sv[j];
    red[t] = s2 * s2;
    __syncthreads();
    if (t == 0) {
        float a = 0.f;
        for (int i = 0; i < F; ++i) a += red[i];
        float nt = sqrtf(a);
        float sigma = a / (nt + 1e-12f);
        inv_sigma[0] = 1.0f / sigma;
    }
}

// ---------------- init: deg=1 (self loop), cnt=0 ----------------
__global__ __launch_bounds__(256) void init_k(float* __restrict__ deg, int* __restrict__ cnt, int n) {
    int i = blockIdx.x * 256 + threadIdx.x;
    if (i < n) { deg[i] = 1.0f; cnt[i] = 0; }
}

// ---------------- per-edge: weighted degree + in-degree count ----------------
__global__ __launch_bounds__(256) void count_k(const int* __restrict__ col,
                                               const float* __restrict__ wt,
                                               float* __restrict__ deg,
                                               int* __restrict__ cnt, int e_cnt) {
    int e = blockIdx.x * 256 + threadIdx.x;
    if (e < e_cnt) {
        int c = col[e];
        float w = 1.0f / (1.0f + expf(-wt[e]));  // sigmoid
        atomicAdd(deg + c, w);
        atomicAdd(cnt + c, 1);
    }
}

// ---------------- x (fp32) -> xh (bf16) ----------------
__global__ __launch_bounds__(256) void conv_k(const float* __restrict__ x,
                                              bf16_t* __restrict__ xh, int total8) {
    int i = blockIdx.x * 256 + threadIdx.x;  // 8 elems per thread
    if (i < total8) {
        const float4* p = (const float4*)x + (size_t)i * 2;
        float4 a = p[0], b = p[1];
        bf16x8 v;
        v[0] = (bf16_t)a.x; v[1] = (bf16_t)a.y; v[2] = (bf16_t)a.z; v[3] = (bf16_t)a.w;
        v[4] = (bf16_t)b.x; v[5] = (bf16_t)b.y; v[6] = (bf16_t)b.z; v[7] = (bf16_t)b.w;
        *(bf16x8*)(xh + (size_t)i * 8) = v;
    }
}

// ---------------- scan pass 1 (block sums) + fused deg -> dinv ----------------
#define STILE 1024
__global__ __launch_bounds__(256) void scan1_k(const int* __restrict__ cnt,
                                               int* __restrict__ bsum,
                                               float* __restrict__ deg, int n) {
    __shared__ int red[256];
    int t = threadIdx.x;
    int base = blockIdx.x * STILE + t * 4;
    int s = 0;
    if (base + 3 < n) { int4 v = *(const int4*)(cnt + base); s = v.x + v.y + v.z + v.w; }
    else { for (int i = 0; i < 4; ++i) if (base + i < n) s += cnt[base + i]; }
    // fused dinv: deg -> deg^-1/2
    for (int i = 0; i < 4; ++i) {
        if (base + i < n) {
            float d = deg[base + i];
            deg[base + i] = (d > 0.f) ? (1.0f / sqrtf(d)) : 0.0f;
        }
    }
    red[t] = s;
    __syncthreads();
    for (int o = 128; o > 0; o >>= 1) { if (t < o) red[t] += red[t + o]; __syncthreads(); }
    if (t == 0) bsum[blockIdx.x] = red[0];
}

__global__ void scan2_k(int* __restrict__ bsum, int g, int* __restrict__ offsets, int n) {
    if (threadIdx.x == 0 && blockIdx.x == 0) {
        int acc = 0;
        for (int i = 0; i < g; ++i) { int v = bsum[i]; bsum[i] = acc; acc += v; }
        offsets[n] = acc;  // == E
    }
}

__global__ __launch_bounds__(256) void scan3_k(const int* __restrict__ cnt,
                                               const int* __restrict__ bsum,
                                               int* __restrict__ offsets,
                                               int* __restrict__ cursor, int n) {
    __shared__ int sc[256];
    int t = threadIdx.x;
    int base = blockIdx.x * STILE + t * 4;
    int v[4] = {0, 0, 0, 0};
    if (base + 3 < n) { int4 q = *(const int4*)(cnt + base); v[0] = q.x; v[1] = q.y; v[2] = q.z; v[3] = q.w; }
    else { for (int i = 0; i < 4; ++i) if (base + i < n) v[i] = cnt[base + i]; }
    int ts = v[0] + v[1] + v[2] + v[3];
    sc[t] = ts;
    __syncthreads();
    for (int o = 1; o < 256; o <<= 1) {
        int val = sc[t];
        int add = (t >= o) ? sc[t - o] : 0;
        __syncthreads();
        sc[t] = val + add;
        __syncthreads();
    }
    int run = bsum[blockIdx.x] + sc[t] - ts;  // exclusive base for this thread
    for (int i = 0; i < 4; ++i) {
        if (base + i < n) { offsets[base + i] = run; cursor[base + i] = run; }
        run += v[i];
    }
}

// ---------------- counting-sort fill: packed (src, norm) per destination ----------------
__global__ __launch_bounds__(256) void fill_k(const int* __restrict__ row,
                                              const int* __restrict__ col,
                                              const float* __restrict__ wt,
                                              const float* __restrict__ dinv,
                                              int* __restrict__ cursor,
                                              int2* __restrict__ edat, int e_cnt) {
    int e = blockIdx.x * 256 + threadIdx.x;
    if (e < e_cnt) {
        int r = row[e], c = col[e];
        float w = 1.0f / (1.0f + expf(-wt[e]));
        float nv = dinv[r] * w * dinv[c];
        int p = atomicAdd(cursor + c, 1);
        edat[p] = make_int2(r, __float_as_int(nv));
    }
}

// ---------------- gather: one wave per destination node, 4-way load ILP ----------------
// USE_BF16: gather neighbor rows from xh (bf16, 4 B/lane/edge); else fp32 x (8 B).
template <int USE_BF16>
__global__ __launch_bounds__(256) void gather_t(const int* __restrict__ offsets,
                                                const int2* __restrict__ edat,
                                                const float* __restrict__ dinv,
                                                const float* __restrict__ x,
                                                const bf16_t* __restrict__ xh,
                                                float* __restrict__ out, int n) {
    int node = blockIdx.x * 4 + (threadIdx.x >> 6);
    if (node >= n) return;
    int lane = threadIdx.x & 63;
    const float2* x2 = (const float2*)x;
    float dv = dinv[node];
    float2 xv = x2[(size_t)node * 64 + lane];
    float2 acc;
    acc.x = dv * dv * xv.x;  // self loop: norm = dinv*1*dinv
    acc.y = dv * dv * xv.y;
    int s = offsets[node], e = offsets[node + 1];
    for (int b = s; b < e; b += 64) {
        int cnt = min(64, e - b);
        int2 ed = make_int2(0, 0);
        if (lane < cnt) ed = edat[b + lane];
        int j = 0;
        for (; j + 4 <= cnt; j += 4) {
            int r0 = __shfl(ed.x, j + 0), r1 = __shfl(ed.x, j + 1);
            int r2 = __shfl(ed.x, j + 2), r3 = __shfl(ed.x, j + 3);
            float n0 = __int_as_float(__shfl(ed.y, j + 0));
            float n1 = __int_as_float(__shfl(ed.y, j + 1));
            float n2 = __int_as_float(__shfl(ed.y, j + 2));
            float n3 = __int_as_float(__shfl(ed.y, j + 3));
            if (USE_BF16) {
                unsigned v0 = *(const unsigned*)(xh + (size_t)r0 * F) + 0;  // placeholder, replaced below
                // (re-load properly with lane offset)
                v0 = ((const unsigned*)(xh + (size_t)r0 * F))[lane];
                unsigned v1 = ((const unsigned*)(xh + (size_t)r1 * F))[lane];
                unsigned v2 = ((const unsigned*)(xh + (size_t)r2 * F))[lane];
                unsigned v3 = ((const unsigned*)(xh + (size_t)r3 * F))[lane];
                acc.x = fmaf(n0, __uint_as_float(v0 << 16), acc.x);
                acc.y = fmaf(n0, __uint_as_float(v0 & 0xFFFF0000u), acc.y);
                acc.x = fmaf(n1, __uint_as_float(v1 << 16), acc.x);
                acc.y = fmaf(n1, __uint_as_float(v1 & 0xFFFF0000u), acc.y);
                acc.x = fmaf(n2, __uint_as_float(v2 << 16), acc.x);
                acc.y = fmaf(n2, __uint_as_float(v2 & 0xFFFF0000u), acc.y);
                acc.x = fmaf(n3, __uint_as_float(v3 << 16), acc.x);
                acc.y = fmaf(n3, __uint_as_float(v3 & 0xFFFF0000u), acc.y);
            } else {
                float2 a0 = x2[(size_t)r0 * 64 + lane];
                float2 a1 = x2[(size_t)r1 * 64 + lane];
                float2 a2 = x2[(size_t)r2 * 64 + lane];
                float2 a3 = x2[(size_t)r3 * 64 + lane];
                acc.x = fmaf(n0, a0.x, acc.x); acc.y = fmaf(n0, a0.y, acc.y);
                acc.x = fmaf(n1, a1.x, acc.x); acc.y = fmaf(n1, a1.y, acc.y);
                acc.x = fmaf(n2, a2.x, acc.x); acc.y = fmaf(n2, a2.y, acc.y);
                acc.x = fmaf(n3, a3.x, acc.x); acc.y = fmaf(n3, a3.y, acc.y);
            }
        }
        for (; j < cnt; ++j) {
            int r = __shfl(ed.x, j);
            float nv = __int_as_float(__shfl(ed.y, j));
            if (USE_BF16) {
                unsigned v = ((const unsigned*)(xh + (size_t)r * F))[lane];
                acc.x = fmaf(nv, __uint_as_float(v << 16), acc.x);
                acc.y = fmaf(nv, __uint_as_float(v & 0xFFFF0000u), acc.y);
            } else {
                float2 xr = x2[(size_t)r * 64 + lane];
                acc.x = fmaf(nv, xr.x, acc.x);
                acc.y = fmaf(nv, xr.y, acc.y);
            }
        }
    }
    ((float2*)out)[(size_t)node * 64 + lane] = acc;
}

// ---------------- Wt[n][k] = bf16(W[k][n] * inv_sigma) ----------------
__global__ __launch_bounds__(256) void wt_k(const float* __restrict__ W,
                                            const float* __restrict__ invs,
                                            bf16_t* __restrict__ Wt) {
    float is = invs[0];
    int t = blockIdx.x * 256 + threadIdx.x;  // 16384 total
    int k = t >> 7, n = t & 127;
    Wt[n * F + k] = (bf16_t)(W[k * F + n] * is);
}

// ---------------- MFMA GEMM (in place): io = bf16(io) @ Wn + bias ----------------
#define GBM 64
#define LDK 136  // 128 + 8 pad
__global__ __launch_bounds__(256) void gemm_mfma_k(float* __restrict__ io,
                                                   const bf16_t* __restrict__ Wt,
                                                   const float* __restrict__ bias,
                                                   int nrows) {
    __shared__ bf16_t As[GBM * LDK];
    __shared__ bf16_t Ws[F * LDK];
    int tid = threadIdx.x;
    int rowBase = blockIdx.x * GBM;

    for (int i = tid; i < GBM * 32; i += 256) {  // float4 chunks
        int r = i >> 5, c4 = (i & 31) * 4;
        float4 xv = make_float4(0.f, 0.f, 0.f, 0.f);
        if (rowBase + r < nrows) xv = *(const float4*)(io + (size_t)(rowBase + r) * F + c4);
        bf16x4 v;
        v.x = (bf16_t)xv.x; v.y = (bf16_t)xv.y; v.z = (bf16_t)xv.z; v.w = (bf16_t)xv.w;
        *(bf16x4*)(As + r * LDK + c4) = v;
    }
    for (int i = tid; i < 2048; i += 256) {  // 16B chunks: 128 rows x 16
        int nrow = i >> 4;
        int c = (i & 15) * 8;
        *(bf16x8*)(Ws + nrow * LDK + c) = *(const bf16x8*)(Wt + nrow * F + c);
    }
    __syncthreads();

    int wave = tid >> 6, lane = tid & 63;
    int l16 = lane & 15, q = lane >> 4;
    int mrow = wave * 16;

    floatx4 acc[8];
#pragma unroll
    for (int nt = 0; nt < 8; ++nt) acc[nt] = (floatx4){0.f, 0.f, 0.f, 0.f};

#pragma unroll
    for (int kt = 0; kt < 4; ++kt) {
        bf16x8 a = *(bf16x8*)(As + (mrow + l16) * LDK + kt * 32 + q * 8);
#pragma unroll
        for (int nt = 0; nt < 8; ++nt) {
            bf16x8 b = *(bf16x8*)(Ws + (nt * 16 + l16) * LDK + kt * 32 + q * 8);
            acc[nt] = __builtin_amdgcn_mfma_f32_16x16x32_bf16(a, b, acc[nt], 0, 0, 0);
        }
    }

#pragma unroll
    for (int nt = 0; nt < 8; ++nt) {
        int col = nt * 16 + l16;
        float bv = bias[col];
#pragma unroll
        for (int r = 0; r < 4; ++r) {
            int grow = rowBase + mrow + q * 4 + r;
            if (grow < nrows) io[(size_t)grow * F + col] = acc[nt][r] + bv;
        }
    }
}

extern "C" void kernel_launch(void* const* d_in, const int* in_sizes, int n_in,
                              void* d_out, int out_size, void* d_ws, size_t ws_size,
                              hipStream_t stream) {
    const float* x    = (const float*)d_in[0];
    const int*   ei   = (const int*)d_in[1];
    const float* ewt  = (const float*)d_in[2];
    const float* W    = (const float*)d_in[3];
    const float* bias = (const float*)d_in[4];
    const float* u    = (const float*)d_in[5];
    float* out = (float*)d_out;

    int n_nodes = in_sizes[0] / F;
    int e_cnt   = in_sizes[2];
    const int* row = ei;
    const int* col = ei + e_cnt;

    // workspace layout
    float* wsf = (float*)d_ws;
    int*   wsi = (int*)d_ws;
    float* invs    = wsf;                          // 64
    float* dinv    = wsf + 64;                     // N  (deg -> dinv in place)
    int*   cnt     = wsi + 64 + n_nodes;           // N
    int*   offsets = cnt + n_nodes;                // N+1
    int*   cursor  = offsets + n_nodes + 1;        // N
    int*   bsum    = cursor + n_nodes;             // 128
    size_t fixed_bytes = ((size_t)(64 + 4 * n_nodes + 1 + 128) * 4 + 15) & ~(size_t)15;
    int2*  edat    = (int2*)((char*)d_ws + fixed_bytes);            // E int2
    bf16_t* Wt     = (bf16_t*)((char*)edat + (size_t)e_cnt * 8);    // 128x128 bf16
    bf16_t* xh     = (bf16_t*)((char*)Wt + (size_t)F * F * 2);      // N*128 bf16
    size_t need_bf16 = (size_t)((char*)xh - (char*)d_ws) + (size_t)n_nodes * F * 2;
    int use_bf16 = (ws_size >= need_bf16);

    int g_scan = (n_nodes + STILE - 1) / STILE;

    spectral_k<<<1, 128, 0, stream>>>(W, u, invs);
    init_k<<<(n_nodes + 255) / 256, 256, 0, stream>>>(dinv, cnt, n_nodes);
    count_k<<<(e_cnt + 255) / 256, 256, 0, stream>>>(col, ewt, dinv, cnt, e_cnt);
    if (use_bf16) {
        int total8 = n_nodes * (F / 8);
        conv_k<<<(total8 + 255) / 256, 256, 0, stream>>>(x, xh, total8);
    }
    scan1_k<<<g_scan, 256, 0, stream>>>(cnt, bsum, dinv, n_nodes);
    scan2_k<<<1, 64, 0, stream>>>(bsum, g_scan, offsets, n_nodes);
    scan3_k<<<g_scan, 256, 0, stream>>>(cnt, bsum, offsets, cursor, n_nodes);
    fill_k<<<(e_cnt + 255) / 256, 256, 0, stream>>>(row, col, ewt, dinv, cursor, edat, e_cnt);
    if (use_bf16) {
        gather_t<1><<<(n_nodes + 3) / 4, 256, 0, stream>>>(offsets, edat, dinv, x, xh, out, n_nodes);
    } else {
        gather_t<0><<<(n_nodes + 3) / 4, 256, 0, stream>>>(offsets, edat, dinv, x, xh, out, n_nodes);
    }
    wt_k<<<64, 256, 0, stream>>>(W, invs, Wt);
    gemm_mfma_k<<<(n_nodes + GBM - 1) / GBM, 256, 0, stream>>>(out, Wt, bias, n_nodes);
}

// Round 5
// 269.994 us; speedup vs baseline: 2.6620x; 1.1062x over previous
//
#include <hip/hip_runtime.h>
#include <math.h>

#define F 128

typedef __bf16 bf16_t;
typedef unsigned long long u64;
typedef __attribute__((ext_vector_type(8))) bf16_t bf16x8;
typedef __attribute__((ext_vector_type(4))) bf16_t bf16x4;
typedef __attribute__((ext_vector_type(4))) float floatx4;

#define DEG_SCALE 8388608.0f       // 2^23 fixed-point for weighted degree
#define DEG_INV   (1.0f / 8388608.0f)

// ---------------- spectral norm + Wt build (fused, one block) ----------------
// sigma via one power iteration; then Wt[n][k] = bf16(W[k][n] / sigma)
__global__ __launch_bounds__(128) void spectral_wt_k(const float* __restrict__ W,
                                                     const float* __restrict__ u,
                                                     bf16_t* __restrict__ Wt) {
    __shared__ float sv[F];
    __shared__ float red[F];
    __shared__ float snorm;
    __shared__ float s_is;
    int t = threadIdx.x;  // 128 threads
    float s = 0.f;
    for (int i = 0; i < F; ++i) s += W[i * F + t] * u[i];
    red[t] = s * s;
    __syncthreads();
    if (t == 0) {
        float a = 0.f;
        for (int i = 0; i < F; ++i) a += red[i];
        snorm = sqrtf(a);
    }
    __syncthreads();
    sv[t] = s / (snorm + 1e-12f);  // v
    __syncthreads();
    float s2 = 0.f;
    for (int j = 0; j < F; ++j) s2 += W[t * F + j] * sv[j];
    red[t] = s2 * s2;
    __syncthreads();
    if (t == 0) {
        float a = 0.f;
        for (int i = 0; i < F; ++i) a += red[i];
        float nt = sqrtf(a);
        float sigma = a / (nt + 1e-12f);
        s_is = 1.0f / sigma;
    }
    __syncthreads();
    float is = s_is;
    // transposed bf16 weight: coalesced 2B stores, W reads are L1/L2-warm
    for (int nrow = 0; nrow < F; ++nrow)
        Wt[nrow * F + t] = (bf16_t)(W[t * F + nrow] * is);
}

// ---------------- init packed degree/count to 0 ----------------
__global__ __launch_bounds__(256) void init_k(u64* __restrict__ dc, int n) {
    int i = blockIdx.x * 256 + threadIdx.x;
    if (i < n) dc[i] = 0ULL;
}

// ---------------- fused: per-edge packed atomic + fp32->bf16 conv ----------------
// blocks [0, gCount): one u64 atomic per edge — hi32 = count, lo32 = fixed-point w
// blocks [gCount, ...): stream x (fp32) -> xh (bf16)
__global__ __launch_bounds__(256) void count_conv_k(const int* __restrict__ col,
                                                    const float* __restrict__ wt,
                                                    u64* __restrict__ dc, int e_cnt,
                                                    const float* __restrict__ x,
                                                    bf16_t* __restrict__ xh, int total8,
                                                    int gCount) {
    int b = blockIdx.x;
    if (b < gCount) {
        int e = b * 256 + threadIdx.x;
        if (e < e_cnt) {
            int c = col[e];
            float w = 1.0f / (1.0f + expf(-wt[e]));  // sigmoid
            u64 pkt = (1ULL << 32) | (u64)(unsigned)rintf(w * DEG_SCALE);
            atomicAdd(dc + c, pkt);
        }
    } else {
        int i = (b - gCount) * 256 + threadIdx.x;  // 8 elems per thread
        if (i < total8) {
            const float4* p = (const float4*)x + (size_t)i * 2;
            float4 a = p[0], bb = p[1];
            bf16x8 v;
            v[0] = (bf16_t)a.x;  v[1] = (bf16_t)a.y;  v[2] = (bf16_t)a.z;  v[3] = (bf16_t)a.w;
            v[4] = (bf16_t)bb.x; v[5] = (bf16_t)bb.y; v[6] = (bf16_t)bb.z; v[7] = (bf16_t)bb.w;
            *(bf16x8*)(xh + (size_t)i * 8) = v;
        }
    }
}

// ---------------- scan pass 1 (block sums of cnt) + fused dinv ----------------
#define STILE 1024
__global__ __launch_bounds__(256) void scan1_k(const u64* __restrict__ dc,
                                               int* __restrict__ bsum,
                                               float* __restrict__ dinv, int n) {
    __shared__ int red[256];
    int t = threadIdx.x;
    int base = blockIdx.x * STILE + t * 4;
    int s = 0;
    for (int i = 0; i < 4; ++i) {
        if (base + i < n) {
            u64 v = dc[base + i];
            s += (int)(v >> 32);
            float d = 1.0f + (float)(unsigned)(v & 0xFFFFFFFFULL) * DEG_INV;
            dinv[base + i] = 1.0f / sqrtf(d);  // d >= 1 always (self loop)
        }
    }
    red[t] = s;
    __syncthreads();
    for (int o = 128; o > 0; o >>= 1) { if (t < o) red[t] += red[t + o]; __syncthreads(); }
    if (t == 0) bsum[blockIdx.x] = red[0];
}

__global__ void scan2_k(int* __restrict__ bsum, int g, int* __restrict__ offsets, int n) {
    if (threadIdx.x == 0 && blockIdx.x == 0) {
        int acc = 0;
        for (int i = 0; i < g; ++i) { int v = bsum[i]; bsum[i] = acc; acc += v; }
        offsets[n] = acc;  // == E
    }
}

__global__ __launch_bounds__(256) void scan3_k(const u64* __restrict__ dc,
                                               const int* __restrict__ bsum,
                                               int* __restrict__ offsets,
                                               int* __restrict__ cursor, int n) {
    __shared__ int sc[256];
    int t = threadIdx.x;
    int base = blockIdx.x * STILE + t * 4;
    int v[4] = {0, 0, 0, 0};
    for (int i = 0; i < 4; ++i)
        if (base + i < n) v[i] = (int)(dc[base + i] >> 32);
    int ts = v[0] + v[1] + v[2] + v[3];
    sc[t] = ts;
    __syncthreads();
    for (int o = 1; o < 256; o <<= 1) {
        int val = sc[t];
        int add = (t >= o) ? sc[t - o] : 0;
        __syncthreads();
        sc[t] = val + add;
        __syncthreads();
    }
    int run = bsum[blockIdx.x] + sc[t] - ts;  // exclusive base for this thread
    for (int i = 0; i < 4; ++i) {
        if (base + i < n) { offsets[base + i] = run; cursor[base + i] = run; }
        run += v[i];
    }
}

// ---------------- counting-sort fill: packed (src, norm) per destination ----------------
__global__ __launch_bounds__(256) void fill_k(const int* __restrict__ row,
                                              const int* __restrict__ col,
                                              const float* __restrict__ wt,
                                              const float* __restrict__ dinv,
                                              int* __restrict__ cursor,
                                              int2* __restrict__ edat, int e_cnt) {
    int e = blockIdx.x * 256 + threadIdx.x;
    if (e < e_cnt) {
        int r = row[e], c = col[e];
        float w = 1.0f / (1.0f + expf(-wt[e]));
        float nv = dinv[r] * w * dinv[c];
        int p = atomicAdd(cursor + c, 1);
        edat[p] = make_int2(r, __float_as_int(nv));
    }
}

// ---------------- gather: one wave per destination node, 4-way load ILP ----------------
template <int USE_BF16>
__global__ __launch_bounds__(256) void gather_t(const int* __restrict__ offsets,
                                                const int2* __restrict__ edat,
                                                const float* __restrict__ dinv,
                                                const float* __restrict__ x,
                                                const bf16_t* __restrict__ xh,
                                                float* __restrict__ out, int n) {
    int node = blockIdx.x * 4 + (threadIdx.x >> 6);
    if (node >= n) return;
    int lane = threadIdx.x & 63;
    const float2* x2 = (const float2*)x;
    float dv = dinv[node];
    float2 xv = x2[(size_t)node * 64 + lane];
    float2 acc;
    acc.x = dv * dv * xv.x;  // self loop: norm = dinv*1*dinv
    acc.y = dv * dv * xv.y;
    int s = offsets[node], e = offsets[node + 1];
    for (int b = s; b < e; b += 64) {
        int cnt = min(64, e - b);
        int2 ed = make_int2(0, 0);
        if (lane < cnt) ed = edat[b + lane];
        int j = 0;
        for (; j + 4 <= cnt; j += 4) {
            int r0 = __shfl(ed.x, j + 0), r1 = __shfl(ed.x, j + 1);
            int r2 = __shfl(ed.x, j + 2), r3 = __shfl(ed.x, j + 3);
            float n0 = __int_as_float(__shfl(ed.y, j + 0));
            float n1 = __int_as_float(__shfl(ed.y, j + 1));
            float n2 = __int_as_float(__shfl(ed.y, j + 2));
            float n3 = __int_as_float(__shfl(ed.y, j + 3));
            if (USE_BF16) {
                unsigned v0 = ((const unsigned*)(xh + (size_t)r0 * F))[lane];
                unsigned v1 = ((const unsigned*)(xh + (size_t)r1 * F))[lane];
                unsigned v2 = ((const unsigned*)(xh + (size_t)r2 * F))[lane];
                unsigned v3 = ((const unsigned*)(xh + (size_t)r3 * F))[lane];
                acc.x = fmaf(n0, __uint_as_float(v0 << 16), acc.x);
                acc.y = fmaf(n0, __uint_as_float(v0 & 0xFFFF0000u), acc.y);
                acc.x = fmaf(n1, __uint_as_float(v1 << 16), acc.x);
                acc.y = fmaf(n1, __uint_as_float(v1 & 0xFFFF0000u), acc.y);
                acc.x = fmaf(n2, __uint_as_float(v2 << 16), acc.x);
                acc.y = fmaf(n2, __uint_as_float(v2 & 0xFFFF0000u), acc.y);
                acc.x = fmaf(n3, __uint_as_float(v3 << 16), acc.x);
                acc.y = fmaf(n3, __uint_as_float(v3 & 0xFFFF0000u), acc.y);
            } else {
                float2 a0 = x2[(size_t)r0 * 64 + lane];
                float2 a1 = x2[(size_t)r1 * 64 + lane];
                float2 a2 = x2[(size_t)r2 * 64 + lane];
                float2 a3 = x2[(size_t)r3 * 64 + lane];
                acc.x = fmaf(n0, a0.x, acc.x); acc.y = fmaf(n0, a0.y, acc.y);
                acc.x = fmaf(n1, a1.x, acc.x); acc.y = fmaf(n1, a1.y, acc.y);
                acc.x = fmaf(n2, a2.x, acc.x); acc.y = fmaf(n2, a2.y, acc.y);
                acc.x = fmaf(n3, a3.x, acc.x); acc.y = fmaf(n3, a3.y, acc.y);
            }
        }
        for (; j < cnt; ++j) {
            int r = __shfl(ed.x, j);
            float nv = __int_as_float(__shfl(ed.y, j));
            if (USE_BF16) {
                unsigned v = ((const unsigned*)(xh + (size_t)r * F))[lane];
                acc.x = fmaf(nv, __uint_as_float(v << 16), acc.x);
                acc.y = fmaf(nv, __uint_as_float(v & 0xFFFF0000u), acc.y);
            } else {
                float2 xr = x2[(size_t)r * 64 + lane];
                acc.x = fmaf(nv, xr.x, acc.x);
                acc.y = fmaf(nv, xr.y, acc.y);
            }
        }
    }
    ((float2*)out)[(size_t)node * 64 + lane] = acc;
}

// ---------------- MFMA GEMM (in place): io = bf16(io) @ Wn + bias ----------------
#define GBM 64
#define LDK 136  // 128 + 8 pad
__global__ __launch_bounds__(256) void gemm_mfma_k(float* __restrict__ io,
                                                   const bf16_t* __restrict__ Wt,
                                                   const float* __restrict__ bias,
                                                   int nrows) {
    __shared__ bf16_t As[GBM * LDK];
    __shared__ bf16_t Ws[F * LDK];
    int tid = threadIdx.x;
    int rowBase = blockIdx.x * GBM;

    for (int i = tid; i < GBM * 32; i += 256) {  // float4 chunks
        int r = i >> 5, c4 = (i & 31) * 4;
        float4 xv = make_float4(0.f, 0.f, 0.f, 0.f);
        if (rowBase + r < nrows) xv = *(const float4*)(io + (size_t)(rowBase + r) * F + c4);
        bf16x4 v;
        v.x = (bf16_t)xv.x; v.y = (bf16_t)xv.y; v.z = (bf16_t)xv.z; v.w = (bf16_t)xv.w;
        *(bf16x4*)(As + r * LDK + c4) = v;
    }
    for (int i = tid; i < 2048; i += 256) {  // 16B chunks: 128 rows x 16
        int nrow = i >> 4;
        int c = (i & 15) * 8;
        *(bf16x8*)(Ws + nrow * LDK + c) = *(const bf16x8*)(Wt + nrow * F + c);
    }
    __syncthreads();

    int wave = tid >> 6, lane = tid & 63;
    int l16 = lane & 15, q = lane >> 4;
    int mrow = wave * 16;

    floatx4 acc[8];
#pragma unroll
    for (int nt = 0; nt < 8; ++nt) acc[nt] = (floatx4){0.f, 0.f, 0.f, 0.f};

#pragma unroll
    for (int kt = 0; kt < 4; ++kt) {
        bf16x8 a = *(bf16x8*)(As + (mrow + l16) * LDK + kt * 32 + q * 8);
#pragma unroll
        for (int nt = 0; nt < 8; ++nt) {
            bf16x8 b = *(bf16x8*)(Ws + (nt * 16 + l16) * LDK + kt * 32 + q * 8);
            acc[nt] = __builtin_amdgcn_mfma_f32_16x16x32_bf16(a, b, acc[nt], 0, 0, 0);
        }
    }

#pragma unroll
    for (int nt = 0; nt < 8; ++nt) {
        int col = nt * 16 + l16;
        float bv = bias[col];
#pragma unroll
        for (int r = 0; r < 4; ++r) {
            int grow = rowBase + mrow + q * 4 + r;
            if (grow < nrows) io[(size_t)grow * F + col] = acc[nt][r] + bv;
        }
    }
}

extern "C" void kernel_launch(void* const* d_in, const int* in_sizes, int n_in,
                              void* d_out, int out_size, void* d_ws, size_t ws_size,
                              hipStream_t stream) {
    const float* x    = (const float*)d_in[0];
    const int*   ei   = (const int*)d_in[1];
    const float* ewt  = (const float*)d_in[2];
    const float* W    = (const float*)d_in[3];
    const float* bias = (const float*)d_in[4];
    const float* u    = (const float*)d_in[5];
    float* out = (float*)d_out;

    int n_nodes = in_sizes[0] / F;
    int e_cnt   = in_sizes[2];
    const int* row = ei;
    const int* col = ei + e_cnt;

    // workspace layout
    char* wsb = (char*)d_ws;
    float* dinv    = (float*)wsb;                                   // N floats
    size_t off = ((size_t)n_nodes * 4 + 7) & ~(size_t)7;
    u64*   dc      = (u64*)(wsb + off);                             // N u64 (cnt<<32 | fixed deg)
    off += (size_t)n_nodes * 8;
    int*   offsets = (int*)(wsb + off);                             // N+1
    off += (size_t)(n_nodes + 1) * 4;
    int*   cursor  = (int*)(wsb + off);                             // N
    off += (size_t)n_nodes * 4;
    int*   bsum    = (int*)(wsb + off);                             // 128
    off += 128 * 4;
    off = (off + 7) & ~(size_t)7;
    int2*  edat    = (int2*)(wsb + off);                            // E int2
    off += (size_t)e_cnt * 8;
    bf16_t* Wt     = (bf16_t*)(wsb + off);                          // 128x128 bf16
    off += (size_t)F * F * 2;
    bf16_t* xh     = (bf16_t*)(wsb + off);                          // N*128 bf16
    size_t need_bf16 = off + (size_t)n_nodes * F * 2;
    int use_bf16 = (ws_size >= need_bf16);

    int g_scan  = (n_nodes + STILE - 1) / STILE;
    int gCount  = (e_cnt + 255) / 256;
    int total8  = n_nodes * (F / 8);
    int gConv   = use_bf16 ? (total8 + 255) / 256 : 0;

    spectral_wt_k<<<1, 128, 0, stream>>>(W, u, Wt);
    init_k<<<(n_nodes + 255) / 256, 256, 0, stream>>>(dc, n_nodes);
    count_conv_k<<<gCount + gConv, 256, 0, stream>>>(col, ewt, dc, e_cnt, x, xh, total8, gCount);
    scan1_k<<<g_scan, 256, 0, stream>>>(dc, bsum, dinv, n_nodes);
    scan2_k<<<1, 64, 0, stream>>>(bsum, g_scan, offsets, n_nodes);
    scan3_k<<<g_scan, 256, 0, stream>>>(dc, bsum, offsets, cursor, n_nodes);
    fill_k<<<(e_cnt + 255) / 256, 256, 0, stream>>>(row, col, ewt, dinv, cursor, edat, e_cnt);
    if (use_bf16) {
        gather_t<1><<<(n_nodes + 3) / 4, 256, 0, stream>>>(offsets, edat, dinv, x, xh, out, n_nodes);
    } else {
        gather_t<0><<<(n_nodes + 3) / 4, 256, 0, stream>>>(offsets, edat, dinv, x, xh, out, n_nodes);
    }
    gemm_mfma_k<<<(n_nodes + GBM - 1) / GBM, 256, 0, stream>>>(out, Wt, bias, n_nodes);
}